// Round 9
// baseline (506.194 us; speedup 1.0000x reference)
//
#include <hip/hip_runtime.h>
#include <cstdint>

#define T_ 32
#define N_ 5000
#define E_ 80000
#define H_ 128
#define HD_ 512
#define C_ 10

typedef _Float16 f16;
typedef f16 f16x8 __attribute__((ext_vector_type(8)));
typedef f16 f16x4 __attribute__((ext_vector_type(4)));
typedef f16 f16x2 __attribute__((ext_vector_type(2)));
typedef float f32x4 __attribute__((ext_vector_type(4)));

#define LDA 136   // padded LDS leading dim in f16
#define NB_ 8     // CSR-build blocks per graph
#define EPS_ (E_ / NB_)  // 10000 edges per block
#define NBLK_ 313 // ceil(N_/16) node/row blocks per graph (aggr + gemm tasks)
#define GEMMB 768 // gemm grid: 96 blocks/XCD * 8 (3 blocks/CU at 52KB LDS)

__device__ inline int addpk(int a, int b) {
    f16x2 x = __builtin_bit_cast(f16x2, a);
    f16x2 y = __builtin_bit_cast(f16x2, b);
    f16x2 r = x + y;
    return __builtin_bit_cast(int, r);
}

__device__ inline float fast_tanh(float x) {
    return 1.0f - 2.0f / (__expf(2.0f * x) + 1.0f);
}

__device__ inline f16x8 cvt8(float4 a, float4 b) {
    return (f16x8){(f16)a.x, (f16)a.y, (f16)a.z, (f16)a.w,
                   (f16)b.x, (f16)b.y, (f16)b.z, (f16)b.w};
}

// ---------------- CSR build, LDS-atomic (no global atomics) ----------------
__global__ __launch_bounds__(256) void k_count(const int* __restrict__ ei, int* __restrict__ part) {
    __shared__ int cnt[N_];
    int blk = blockIdx.x;
    int t = blk & 31, seg = blk >> 5;
    int tid = threadIdx.x;
    for (int i = tid; i < N_; i += 256) cnt[i] = 0;
    __syncthreads();
    const int* dst = ei + (size_t)t * 2 * E_ + E_ + seg * EPS_;
    for (int e = tid * 4; e < EPS_; e += 1024) {
        int4 d = *(const int4*)&dst[e];
        atomicAdd(&cnt[d.x], 1);
        atomicAdd(&cnt[d.y], 1);
        atomicAdd(&cnt[d.z], 1);
        atomicAdd(&cnt[d.w], 1);
    }
    __syncthreads();
    int* p = part + (t * NB_ + seg) * N_;
    for (int i = tid * 4; i < N_; i += 1024) *(int4*)&p[i] = *(const int4*)&cnt[i];
}

// ---------------- scan v2: coalesced degree/fixup phases, LDS-staged scan ----------------
__global__ __launch_bounds__(256) void k_scan(int* __restrict__ part, int* __restrict__ ptr,
                                              float* __restrict__ dinv, float* __restrict__ z) {
    __shared__ int cnt[N_];      // degree, then start offset
    __shared__ int red[256];
    int t = blockIdx.x, tid = threadIdx.x;
    int base = t * N_;
    if (tid < 128) z[t * 128 + tid] = 0.0f;   // folded zinit (also the aggr zero-row source)
    int* pp = part + t * NB_ * N_;

    // Phase A: coalesced degree computation
    for (int i = tid; i < N_; i += 256) {
        int c = 0;
#pragma unroll
        for (int s = 0; s < NB_; ++s) c += pp[s * N_ + i];
        cnt[i] = c;
        dinv[base + i] = rsqrtf((float)(c + 1));  // +1 self-loop
    }
    __syncthreads();

    // Phase B: block scan over blocked 20-element runs (LDS source)
    int vals[20];
    int sum = 0;
#pragma unroll
    for (int j = 0; j < 20; ++j) {
        int i = tid * 20 + j;
        int c = (i < N_) ? cnt[i] : 0;
        vals[j] = sum;
        sum += c;
    }
    red[tid] = sum;
    __syncthreads();
    for (int off = 1; off < 256; off <<= 1) {
        int v = (tid >= off) ? red[tid - off] : 0;
        __syncthreads();
        red[tid] += v;
        __syncthreads();
    }
    int prev = (tid > 0) ? red[tid - 1] : 0;
#pragma unroll
    for (int j = 0; j < 20; ++j) {
        int i = tid * 20 + j;
        if (i < N_) cnt[i] = prev + vals[j];   // overwrite degree with start offset
    }
    __syncthreads();

    // Phase C: coalesced ptr write + per-segment running-offset fixup
    for (int i = tid; i < N_; i += 256) {
        int run = cnt[i];
        ptr[base + i] = run;
#pragma unroll
        for (int s = 0; s < NB_; ++s) {
            int c = pp[s * N_ + i];
            pp[s * N_ + i] = run;
            run += c;
        }
    }
}

__global__ __launch_bounds__(256) void k_scatter(const int* __restrict__ ei,
                                                 const int* __restrict__ part,
                                                 uint16_t* __restrict__ col) {
    __shared__ int cur[N_];
    int blk = blockIdx.x;
    int t = blk & 31, seg = blk >> 5;
    int tid = threadIdx.x;
    const int* off = part + (t * NB_ + seg) * N_;
    for (int i = tid * 4; i < N_; i += 1024) *(int4*)&cur[i] = *(const int4*)&off[i];
    __syncthreads();
    const int* src = ei + (size_t)t * 2 * E_ + seg * EPS_;
    const int* dst = src + E_;
    uint16_t* cl = col + (size_t)t * E_;
    for (int e = tid * 4; e < EPS_; e += 1024) {
        int4 s4 = *(const int4*)&src[e];
        int4 d4 = *(const int4*)&dst[e];
        cl[atomicAdd(&cur[d4.x], 1)] = (uint16_t)s4.x;
        cl[atomicAdd(&cur[d4.y], 1)] = (uint16_t)s4.y;
        cl[atomicAdd(&cur[d4.z], 1)] = (uint16_t)s4.z;
        cl[atomicAdd(&cur[d4.w], 1)] = (uint16_t)s4.w;
    }
}

// ---------------- weight prep: Wt[l][c][k] = (f16)W_l[k][c] ----------------
__global__ __launch_bounds__(256) void k_wprep(const float* __restrict__ W0,
                                               const float* __restrict__ W1,
                                               const float* __restrict__ W2,
                                               f16* __restrict__ Wt) {
    const float* W = (blockIdx.x == 0) ? W0 : (blockIdx.x == 1) ? W1 : W2;
    f16* dst = Wt + blockIdx.x * 16384;
    for (int idx = threadIdx.x; idx < 16384; idx += 256) {
        int c = idx >> 7, k = idx & 127;
        dst[idx] = (f16)W[k * 128 + c];
    }
}

// ---------------- MFMA GEMM v5: barrier-free streaming (measured keeper) ----------------
// K=128 fits one wave's MFMA fragments: no inter-wave A sharing. Stage Ws once ->
// ONE barrier -> waves grid-stride independent 16-row tasks; A direct global->reg;
// transpose via per-wave private LDS slab (lgkmcnt only); 1KB coalesced stores.
template <bool F32IN>
__global__ __launch_bounds__(256, 3) void k_gemm(const void* __restrict__ in_,
                                                 const f16* __restrict__ Wt,  // [c][k]
                                                 const float* __restrict__ dinv,
                                                 f16* __restrict__ g) {
    __shared__ f16 Ws[128 * LDA];
    __shared__ f16 slab[4][16 * LDA];
    int tid = threadIdx.x;
    {
        int c = tid >> 1, hf = tid & 1;
        const f16* src = Wt + c * 128 + hf * 64;
        f16* dst = Ws + c * LDA + hf * 64;
#pragma unroll
        for (int j = 0; j < 8; ++j) *(f16x8*)&dst[j * 8] = *(const f16x8*)&src[j * 8];
    }
    __syncthreads();   // the ONLY barrier; waves run free below

    int xc = blockIdx.x & 7;
    int jb = blockIdx.x >> 3;            // 0..95 per XCD
    int w = tid >> 6, lane = tid & 63;
    int m = lane & 15, q = lane >> 4;
    int co = q * 8;
    f16* sl = slab[w];
    int srow = lane >> 4;                // store row-within-quad
    int scol = (lane & 15) * 8;          // store col

    for (int task = jb * 4 + w; task < 4 * NBLK_; task += 384) {
        int gsel = task / NBLK_;
        int tile = task - gsel * NBLK_;
        int t = xc + (gsel << 3);
        int base = t * N_;
        int r0 = tile * 16;
        int rowA = r0 + m; if (rowA >= N_) rowA = N_ - 1;   // clamp (not stored)

        // A fragments: direct global -> registers
        f16x8 a0, a1, a2, a3;
        if (F32IN) {
            const float* src = (const float*)in_ + (((size_t)(base + rowA)) << 7) + co;
            float4 u0 = *(const float4*)&src[0];
            float4 u1 = *(const float4*)&src[4];
            float4 u2 = *(const float4*)&src[32];
            float4 u3 = *(const float4*)&src[36];
            float4 u4 = *(const float4*)&src[64];
            float4 u5 = *(const float4*)&src[68];
            float4 u6 = *(const float4*)&src[96];
            float4 u7 = *(const float4*)&src[100];
            a0 = cvt8(u0, u1); a1 = cvt8(u2, u3); a2 = cvt8(u4, u5); a3 = cvt8(u6, u7);
        } else {
            const f16* src = (const f16*)in_ + (((size_t)(base + rowA)) << 7) + co;
            a0 = *(const f16x8*)&src[0];
            a1 = *(const f16x8*)&src[32];
            a2 = *(const f16x8*)&src[64];
            a3 = *(const f16x8*)&src[96];
        }

        f32x4 acc[8];
#pragma unroll
        for (int n = 0; n < 8; ++n) acc[n] = (f32x4){0.f, 0.f, 0.f, 0.f};
#pragma unroll
        for (int n = 0; n < 8; ++n) {
            f16x8 bF = *(const f16x8*)&Ws[(n * 16 + m) * LDA + co];
            acc[n] = __builtin_amdgcn_mfma_f32_16x16x32_f16(a0, bF, acc[n], 0, 0, 0);
        }
#pragma unroll
        for (int n = 0; n < 8; ++n) {
            f16x8 bF = *(const f16x8*)&Ws[(n * 16 + m) * LDA + 32 + co];
            acc[n] = __builtin_amdgcn_mfma_f32_16x16x32_f16(a1, bF, acc[n], 0, 0, 0);
        }
#pragma unroll
        for (int n = 0; n < 8; ++n) {
            f16x8 bF = *(const f16x8*)&Ws[(n * 16 + m) * LDA + 64 + co];
            acc[n] = __builtin_amdgcn_mfma_f32_16x16x32_f16(a2, bF, acc[n], 0, 0, 0);
        }
#pragma unroll
        for (int n = 0; n < 8; ++n) {
            f16x8 bF = *(const f16x8*)&Ws[(n * 16 + m) * LDA + 96 + co];
            acc[n] = __builtin_amdgcn_mfma_f32_16x16x32_f16(a3, bF, acc[n], 0, 0, 0);
        }

        // epilogue: dinv scale -> per-wave slab (transpose) -> coalesced store
#pragma unroll
        for (int i = 0; i < 4; ++i) {
            int rr = q * 4 + i;
            int gr = r0 + rr; if (gr >= N_) gr = N_ - 1;
            float d = dinv[base + gr];
#pragma unroll
            for (int n = 0; n < 8; ++n)
                sl[rr * LDA + n * 16 + m] = (f16)(acc[n][i] * d);
        }
        asm volatile("s_waitcnt lgkmcnt(0)" ::: "memory");  // wave-internal write->read fence
#pragma unroll
        for (int j4 = 0; j4 < 4; ++j4) {
            int row = j4 * 4 + srow;
            f16x8 v = *(const f16x8*)&sl[row * LDA + scol];
            if (r0 + row < N_)
                *(f16x8*)&g[(((size_t)(base + r0 + row)) << 7) + scol] = v;  // 1KB/wave contiguous
        }
    }
}

// ---------------- CSR gather v6: two-bank pipeline, sched_barrier-pinned ----------------
// v4 (single-bank) = 56us, latency-bound: adds wait on same-iteration loads, one
// exposed ~200cy L2 round-trip per 8 edges (12.4 TB/s vs ~34 ceiling). v5's
// two-bank attempt collapsed: compiler SANK the B-loads below the A-adds to save
// regs (VGPR stayed 48). v6 pins the schedule: issue A(8) + B(8) gathers + 2 col
// prefetches, then __builtin_amdgcn_sched_barrier(0), then accumulate. Loads
// cannot sink; next iteration's loads MAY hoist above the adds (back-edge has no
// barrier - desired). launch_bounds(256,3) gives regalloc ~170 VGPR so the two
// live banks (64 VGPR) don't trigger rematerialization.
// Out-of-range lanes redirect via ONE cndmask to a known-zero row (the z buffer:
// zeroed by k_scan, first written by k_reduce AFTER all aggrs; row index
// 320000-5000*t relative to gg). Dead tail-chunk over-execution adds 0.
__global__ __launch_bounds__(256, 3) void k_aggr(const int* __restrict__ ptr,
                                                 const uint16_t* __restrict__ col,
                                                 const f16* __restrict__ g,
                                                 const float* __restrict__ dinv,
                                                 const float* __restrict__ b,
                                                 f16* __restrict__ out) {
    int x = blockIdx.x & 7;
    int j = blockIdx.x >> 3;
    int gsel = j / NBLK_;
    int nb = j - gsel * NBLK_;
    int t = x + (gsel << 3);

    int w = threadIdx.x >> 6;
    int lane = threadIdx.x & 63;
    int q = lane >> 4, m = lane & 15;
    int n0 = nb * 16 + w * 4;    // wave's first node (4-aligned)
    if (n0 >= N_) return;        // tail waves (no barriers in this kernel)
    int base = t * N_;
    const f16* gg = g + (size_t)base * H_;
    const uint16_t* cl = col + (size_t)t * E_;
    int n = n0 + q;              // this 16-lane group's node
    unsigned moB = (unsigned)(m * 8);   // lane's 8-col slice (element offset)

    // CSR bounds for the wave's 4 nodes: one aligned int4 + one scalar
    int4 p4 = *(const int4*)&ptr[base + n0];
    int pend = (n0 + 4 < N_) ? ptr[base + n0 + 4] : E_;
    int begin = (q == 0) ? p4.x : (q == 1) ? p4.y : (q == 2) ? p4.z : p4.w;
    int end   = (q == 0) ? p4.y : (q == 1) ? p4.z : (q == 2) ? p4.w : pend;

    // epilogue operands hoisted (overlap with gathers)
    float dn = dinv[base + n];
    float4 b4a = *(const float4*)&b[m * 8];
    float4 b4b = *(const float4*)&b[m * 8 + 4];

    // zero-row index relative to gg (layout-coupled; see header comment)
    int zidx = 320000 - 5000 * t;

    f16x8 a0 = *(const f16x8*)&gg[((unsigned)n << 7) + moB];  // self-loop row
    f16x8 a1 = {}, a2 = {}, a3 = {}, a4 = {}, a5 = {}, a6 = {}, a7 = {};

    int e0 = begin & ~7;
    int nc = (end - e0 + 7) >> 3;        // chunk count
    unsigned span = (unsigned)(end - begin);
    int elast = (end - 1) & ~7;
    int emax = elast > e0 ? elast : e0;  // clamp target for col prefetch

    uint4 ccA = *(const uint4*)&cl[e0];
    int eB1 = e0 + 8; eB1 = eB1 < emax ? eB1 : emax;
    uint4 ccB = *(const uint4*)&cl[eB1];

    for (int c = 0; c < nc; c += 2) {
        unsigned ebA = (unsigned)(e0 + c * 8 - begin);   // wraps on front pad: redirects
        // ---- bank A: indices + issue 8 gathers ----
        int iA0 = (int)(ccA.x & 0xFFFFu), iA1 = (int)(ccA.x >> 16);
        int iA2 = (int)(ccA.y & 0xFFFFu), iA3 = (int)(ccA.y >> 16);
        int iA4 = (int)(ccA.z & 0xFFFFu), iA5 = (int)(ccA.z >> 16);
        int iA6 = (int)(ccA.w & 0xFFFFu), iA7 = (int)(ccA.w >> 16);
        int sA0 = (ebA + 0 < span) ? iA0 : zidx;
        int sA1 = (ebA + 1 < span) ? iA1 : zidx;
        int sA2 = (ebA + 2 < span) ? iA2 : zidx;
        int sA3 = (ebA + 3 < span) ? iA3 : zidx;
        int sA4 = (ebA + 4 < span) ? iA4 : zidx;
        int sA5 = (ebA + 5 < span) ? iA5 : zidx;
        int sA6 = (ebA + 6 < span) ? iA6 : zidx;
        int sA7 = (ebA + 7 < span) ? iA7 : zidx;
        f16x8 vA0 = *(const f16x8*)&gg[((unsigned)sA0 << 7) + moB];
        f16x8 vA1 = *(const f16x8*)&gg[((unsigned)sA1 << 7) + moB];
        f16x8 vA2 = *(const f16x8*)&gg[((unsigned)sA2 << 7) + moB];
        f16x8 vA3 = *(const f16x8*)&gg[((unsigned)sA3 << 7) + moB];
        f16x8 vA4 = *(const f16x8*)&gg[((unsigned)sA4 << 7) + moB];
        f16x8 vA5 = *(const f16x8*)&gg[((unsigned)sA5 << 7) + moB];
        f16x8 vA6 = *(const f16x8*)&gg[((unsigned)sA6 << 7) + moB];
        f16x8 vA7 = *(const f16x8*)&gg[((unsigned)sA7 << 7) + moB];
        // ---- bank B: indices + issue 8 gathers ----
        unsigned ebB = ebA + 8;
        int iB0 = (int)(ccB.x & 0xFFFFu), iB1 = (int)(ccB.x >> 16);
        int iB2 = (int)(ccB.y & 0xFFFFu), iB3 = (int)(ccB.y >> 16);
        int iB4 = (int)(ccB.z & 0xFFFFu), iB5 = (int)(ccB.z >> 16);
        int iB6 = (int)(ccB.w & 0xFFFFu), iB7 = (int)(ccB.w >> 16);
        int sB0 = (ebB + 0 < span) ? iB0 : zidx;
        int sB1 = (ebB + 1 < span) ? iB1 : zidx;
        int sB2 = (ebB + 2 < span) ? iB2 : zidx;
        int sB3 = (ebB + 3 < span) ? iB3 : zidx;
        int sB4 = (ebB + 4 < span) ? iB4 : zidx;
        int sB5 = (ebB + 5 < span) ? iB5 : zidx;
        int sB6 = (ebB + 6 < span) ? iB6 : zidx;
        int sB7 = (ebB + 7 < span) ? iB7 : zidx;
        f16x8 vB0 = *(const f16x8*)&gg[((unsigned)sB0 << 7) + moB];
        f16x8 vB1 = *(const f16x8*)&gg[((unsigned)sB1 << 7) + moB];
        f16x8 vB2 = *(const f16x8*)&gg[((unsigned)sB2 << 7) + moB];
        f16x8 vB3 = *(const f16x8*)&gg[((unsigned)sB3 << 7) + moB];
        f16x8 vB4 = *(const f16x8*)&gg[((unsigned)sB4 << 7) + moB];
        f16x8 vB5 = *(const f16x8*)&gg[((unsigned)sB5 << 7) + moB];
        f16x8 vB6 = *(const f16x8*)&gg[((unsigned)sB6 << 7) + moB];
        f16x8 vB7 = *(const f16x8*)&gg[((unsigned)sB7 << 7) + moB];
        // ---- prefetch next two col chunks (clamped; always valid ws memory) ----
        int eA2 = e0 + (c + 2) * 8; eA2 = eA2 < emax ? eA2 : emax;
        int eB2 = e0 + (c + 3) * 8; eB2 = eB2 < emax ? eB2 : emax;
        uint4 nA = *(const uint4*)&cl[eA2];
        uint4 nB = *(const uint4*)&cl[eB2];
        // ---- PIN: nothing may cross this point (loads stay above, adds below) ----
        __builtin_amdgcn_sched_barrier(0);
        // ---- accumulate A (B + col loads still in flight), then B ----
        a0 += vA0; a1 += vA1; a2 += vA2; a3 += vA3;
        a4 += vA4; a5 += vA5; a6 += vA6; a7 += vA7;
        a0 += vB0; a1 += vB1; a2 += vB2; a3 += vB3;
        a4 += vB4; a5 += vB5; a6 += vB6; a7 += vB7;
        ccA = nA; ccB = nB;
    }
    a0 += a1; a2 += a3; a4 += a5; a6 += a7;
    a0 += a2; a4 += a6;
    a0 += a4;

    f16x8 o;
#pragma unroll
    for (int jj = 0; jj < 8; ++jj) {
        float bj = (jj < 4) ? ((const float*)&b4a)[jj] : ((const float*)&b4b)[jj - 4];
        o[jj] = (f16)fast_tanh(dn * (float)a0[jj] + bj);
    }
    *(f16x8*)&out[((size_t)base + n) * H_ + moB] = o;  // contiguous 1 KB wave store
}

// ---------------- node-sum: z[t][c] = sum_n h[t][n][c] ----------------
__global__ __launch_bounds__(256) void k_reduce(const f16* __restrict__ h, float* __restrict__ z) {
    int t = blockIdx.x, seg = blockIdx.y;
    int tid = threadIdx.x;
    int rg = tid >> 5;
    int c = (tid & 31) * 4;
    const f16* p = h + (size_t)t * N_ * H_;
    float4 acc = make_float4(0.f, 0.f, 0.f, 0.f);
    int n0 = seg * 500;
    for (int n = n0 + rg; n < n0 + 500; n += 8) {
        f16x4 v = *(const f16x4*)&p[(size_t)n * H_ + c];
        acc.x += (float)v[0]; acc.y += (float)v[1]; acc.z += (float)v[2]; acc.w += (float)v[3];
    }
    __shared__ float4 part[256];
    part[tid] = acc;
    __syncthreads();
    if (rg == 0) {
        float4 s = part[tid];
#pragma unroll
        for (int j = 1; j < 8; ++j) {
            float4 v = part[(j << 5) + tid];
            s.x += v.x; s.y += v.y; s.z += v.z; s.w += v.w;
        }
        atomicAdd(&z[t * H_ + c + 0], s.x);
        atomicAdd(&z[t * H_ + c + 1], s.y);
        atomicAdd(&z[t * H_ + c + 2], s.z);
        atomicAdd(&z[t * H_ + c + 3], s.w);
    }
}

// ---------------- head stage 1: q,k,v ----------------
__global__ __launch_bounds__(128) void k_qkv(const float* __restrict__ z,
                                             const float* __restrict__ Wq, const float* __restrict__ bq,
                                             const float* __restrict__ Wk, const float* __restrict__ bk,
                                             const float* __restrict__ Wv, const float* __restrict__ bv,
                                             float* __restrict__ q, float* __restrict__ k,
                                             float* __restrict__ v) {
    int t = blockIdx.x, c = threadIdx.x;
    __shared__ float zs[128];
    zs[c] = z[t * 128 + c];
    __syncthreads();
    float aq = bq[c], ak = bk[c], av = bv[c];
    for (int kk = 0; kk < 128; ++kk) {
        float zv = zs[kk];
        aq += zv * Wq[(kk << 7) + c];
        ak += zv * Wk[(kk << 7) + c];
        av += zv * Wv[(kk << 7) + c];
    }
    q[t * 128 + c] = aq;
    k[t * 128 + c] = ak;
    v[t * 128 + c] = av;
}

// ---------------- head stage 2 ----------------
__global__ __launch_bounds__(256) void k_attnmid(
    const float* __restrict__ q, const float* __restrict__ k, const float* __restrict__ v,
    const float* __restrict__ Wo, const float* __restrict__ bo,
    const float* __restrict__ g2, const float* __restrict__ beta2,
    const float* __restrict__ Wm1, const float* __restrict__ bm1,
    const float* __restrict__ Wm2, const float* __restrict__ bm2,
    float* __restrict__ xr) {
    int t = blockIdx.x, tid = threadIdx.x;
    __shared__ float Ks[32 * 128], Vs[32 * 128];
    __shared__ float qs[128], sc[8 * 32], xa[128], hid[512], ys[128];
    __shared__ float redA[128], redB[128];

    for (int i = tid; i < 32 * 128; i += 256) { Ks[i] = k[i]; Vs[i] = v[i]; }
    if (tid < 128) qs[tid] = q[t * 128 + tid];
    __syncthreads();

    {
        int h = tid >> 5, s = tid & 31;
        float d = 0.0f;
#pragma unroll
        for (int kk = 0; kk < 16; ++kk)
            d += qs[(h << 4) + kk] * Ks[(s << 7) + (h << 4) + kk];
        sc[tid] = d * 0.25f;
    }
    __syncthreads();
    if (tid < 8) {
        float m = -1e30f;
        for (int s = 0; s < 32; ++s) m = fmaxf(m, sc[(tid << 5) + s]);
        float l = 0.0f;
        for (int s = 0; s < 32; ++s) { float e = __expf(sc[(tid << 5) + s] - m); sc[(tid << 5) + s] = e; l += e; }
        float inv = 1.0f / l;
        for (int s = 0; s < 32; ++s) sc[(tid << 5) + s] *= inv;
    }
    __syncthreads();
    if (tid < 128) {
        int h = tid >> 4;
        float o = 0.0f;
        for (int s = 0; s < 32; ++s) o += sc[(h << 5) + s] * Vs[(s << 7) + tid];
        qs[tid] = o;
    }
    __syncthreads();
    if (tid < 128) {
        float a = bo[tid];
        for (int kk = 0; kk < 128; ++kk) a += qs[kk] * Wo[(kk << 7) + tid];
        xa[tid] = a;
    }
    __syncthreads();
    for (int j = tid; j < 512; j += 256) {
        float a = bm1[j];
        for (int kk = 0; kk < 128; ++kk) a += xa[kk] * Wm1[(kk << 9) + j];
        hid[j] = fmaxf(a, 0.0f);
    }
    __syncthreads();
    if (tid < 128) {
        float a = bm2[tid];
        for (int j = 0; j < 512; ++j) a += hid[j] * Wm2[(j << 7) + tid];
        ys[tid] = xa[tid] + a;
    }
    __syncthreads();
    if (tid < 128) { redA[tid] = ys[tid]; redB[tid] = ys[tid] * ys[tid]; }
    __syncthreads();
    for (int off = 64; off > 0; off >>= 1) {
        if (tid < off) { redA[tid] += redA[tid + off]; redB[tid] += redB[tid + off]; }
        __syncthreads();
    }
    float mu = redA[0] * (1.0f / 128.0f);
    float var = redB[0] * (1.0f / 128.0f) - mu * mu;
    float rs = rsqrtf(var + 1e-5f);
    if (tid < 128) {
        float yv = (ys[tid] - mu) * rs * g2[tid] + beta2[tid];
        xr[t * 128 + tid] = fmaxf(yv, 0.0f);
    }
}

// ---------------- head stage 3 ----------------
__global__ __launch_bounds__(128) void k_final(const float* __restrict__ xr,
                                               const float* __restrict__ Wl,
                                               const float* __restrict__ bl,
                                               float* __restrict__ out) {
    int tid = threadIdx.x;
    __shared__ float pooled[128];
    float s = 0.0f;
    for (int t = 0; t < 32; ++t) s += xr[t * 128 + tid];
    pooled[tid] = s;
    __syncthreads();
    if (tid < C_) {
        float a = bl[tid];
        for (int kk = 0; kk < 128; ++kk) a += pooled[kk] * Wl[kk * C_ + tid];
        out[tid] = a;
    }
}

extern "C" void kernel_launch(void* const* d_in, const int* in_sizes, int n_in,
                              void* d_out, int out_size, void* d_ws, size_t ws_size,
                              hipStream_t stream) {
    const float* x  = (const float*)d_in[0];
    const int*   ei = (const int*)d_in[1];
    const float* W0 = (const float*)d_in[2];  const float* b0 = (const float*)d_in[3];
    const float* W1 = (const float*)d_in[4];  const float* b1 = (const float*)d_in[5];
    const float* W2 = (const float*)d_in[6];  const float* b2 = (const float*)d_in[7];
    const float* Wq = (const float*)d_in[8];  const float* bq = (const float*)d_in[9];
    const float* Wk = (const float*)d_in[10]; const float* bk = (const float*)d_in[11];
    const float* Wv = (const float*)d_in[12]; const float* bv = (const float*)d_in[13];
    const float* Wo = (const float*)d_in[14]; const float* bo = (const float*)d_in[15];
    const float* g2 = (const float*)d_in[16]; const float* beta2 = (const float*)d_in[17];
    const float* Wm1 = (const float*)d_in[18]; const float* bm1 = (const float*)d_in[19];
    const float* Wm2 = (const float*)d_in[20]; const float* bm2 = (const float*)d_in[21];
    const float* Wl = (const float*)d_in[22]; const float* bl = (const float*)d_in[23];
    float* outp = (float*)d_out;

    const size_t BIG = (size_t)T_ * N_ * H_;
    char* ws = (char*)d_ws;
    float*    dinv = (float*)(ws);
    int*      ptr  = (int*)(ws + 640000);
    uint16_t* col  = (uint16_t*)(ws + 1280000);
    f16*      Wt   = (f16*)(ws + 6400000);
    f16*      P16  = (f16*)(ws + 6498304);
    f16*      Q16  = P16 + BIG;
    float*    z    = (float*)(Q16 + BIG);   // NOTE: k_aggr's zero-row aliases z[0..63]
    float*    zq   = z + 4096;
    float*    zk   = zq + 4096;
    float*    zv   = zk + 4096;
    float*    xr   = zv + 4096;
    int*      part = (int*)P16;   // CSR partials alias P16 (used only before first gemm)

    k_wprep<<<3, 256, 0, stream>>>(W0, W1, W2, Wt);
    k_count<<<NB_ * 32, 256, 0, stream>>>(ei, part);
    k_scan<<<T_, 256, 0, stream>>>(part, ptr, dinv, z);
    k_scatter<<<NB_ * 32, 256, 0, stream>>>(ei, part, col);

    const float* bl_[3] = {b0, b1, b2};
    const int AGGR_BLOCKS = NBLK_ * 32;   // 16 nodes/block, 4 nodes/wave
    k_gemm<true><<<GEMMB, 256, 0, stream>>>(x, Wt, dinv, P16);
    k_aggr<<<AGGR_BLOCKS, 256, 0, stream>>>(ptr, col, P16, dinv, bl_[0], Q16);
    k_gemm<false><<<GEMMB, 256, 0, stream>>>(Q16, Wt + 16384, dinv, P16);
    k_aggr<<<AGGR_BLOCKS, 256, 0, stream>>>(ptr, col, P16, dinv, bl_[1], Q16);
    k_gemm<false><<<GEMMB, 256, 0, stream>>>(Q16, Wt + 32768, dinv, P16);
    k_aggr<<<AGGR_BLOCKS, 256, 0, stream>>>(ptr, col, P16, dinv, bl_[2], Q16);

    k_reduce<<<dim3(T_, 10), 256, 0, stream>>>(Q16, z);

    k_qkv<<<T_, 128, 0, stream>>>(z, Wq, bq, Wk, bk, Wv, bv, zq, zk, zv);
    k_attnmid<<<T_, 256, 0, stream>>>(zq, zk, zv, Wo, bo, g2, beta2,
                                      Wm1, bm1, Wm2, bm2, xr);
    k_final<<<1, 128, 0, stream>>>(xr, Wl, bl, outp);
}